// Round 2
// baseline (3399.911 us; speedup 1.0000x reference)
//
#include <hip/hip_runtime.h>
#include <hip/hip_fp16.h>
#include <cmath>

#define HH 256
#define WW 256
#define TT 48
#define PLANE (HH * WW * TT)

#if defined(__has_builtin)
#if __has_builtin(__builtin_amdgcn_exp2f)
#define EXP2F(x) __builtin_amdgcn_exp2f(x)
#else
#define EXP2F(x) exp2f(x)
#endif
#else
#define EXP2F(x) exp2f(x)
#endif

typedef _Float16 half8 __attribute__((ext_vector_type(8)));
union F4 { float4 v; float f[4]; };
union F2 { float2 v; float f[2]; };

// ---------------- prep: pack gate stream ----------------
// pk[pixel] = {sg3, sg4, sg5, r6, nu0, nu1, q0, q1}  (fp16, 16B)
//   sg_c = sqrt(sig_c*log2e)*g_c (c=3,4,5);  r6 = ||sg|| over channels {0,1,2,6,7,8}
//   nu_c = sqrt(2*spp)*e_c (c=0,1);          q_c = spp*e^2 - T2*v (c=0,1)
__global__ __launch_bounds__(256)
void prep_pack(const float* __restrict__ guidance,
               const float* __restrict__ estimands,
               const float* __restrict__ variance,
               const float* __restrict__ sigma_inv,
               const int* __restrict__ spp_ptr,
               half8* __restrict__ pk)
{
    const int idx = ((int)blockIdx.x * 256 + (int)threadIdx.x) * 4;
    const float sppf = (float)(*spp_ptr);
    const float T2f  = 2.8070337683438042f * 2.8070337683438042f;
    const float squ  = sqrtf(2.0f * sppf);
    const float L2E  = 1.4426950408889634f;
    float sq[9];
#pragma unroll
    for (int g = 0; g < 9; ++g) sq[g] = sqrtf(sigma_inv[g] * L2E);

    F4 gg[9];
#pragma unroll
    for (int g = 0; g < 9; ++g) gg[g].v = *(const float4*)(guidance + (size_t)g * PLANE + idx);
    F4 e0, e1, v0, v1;
    e0.v = *(const float4*)(estimands + 0 * (size_t)PLANE + idx);
    e1.v = *(const float4*)(estimands + 1 * (size_t)PLANE + idx);
    v0.v = *(const float4*)(variance  + 0 * (size_t)PLANE + idx);
    v1.v = *(const float4*)(variance  + 1 * (size_t)PLANE + idx);

#pragma unroll
    for (int s = 0; s < 4; ++s) {
        float r6sq = 0.0f;
#pragma unroll
        for (int g = 0; g < 9; ++g) {
            if (g >= 3 && g < 6) continue;
            const float t = sq[g] * gg[g].f[s];
            r6sq = fmaf(t, t, r6sq);
        }
        half8 h;
        h[0] = (_Float16)(sq[3] * gg[3].f[s]);
        h[1] = (_Float16)(sq[4] * gg[4].f[s]);
        h[2] = (_Float16)(sq[5] * gg[5].f[s]);
        h[3] = (_Float16)sqrtf(r6sq);
        h[4] = (_Float16)(squ * e0.f[s]);
        h[5] = (_Float16)(squ * e1.f[s]);
        h[6] = (_Float16)fmaf(sppf * e0.f[s], e0.f[s], -T2f * v0.f[s]);
        h[7] = (_Float16)fmaf(sppf * e1.f[s], e1.f[s], -T2f * v1.f[s]);
        pk[idx + s] = h;
    }
}

// ---------------- main ----------------
// Thread owns 1 x-column x 6 t-centers. Block: 8 x * 8 tg = 64 (1 wave), grid (W/8, H).
// No __syncthreads anywhere: LDS is pure per-thread scratch (24 slots + 1 pad).
// Residency target: 24 one-wave blocks/CU (LDS 24*6400B = 153.6KB, VGPR <= 85).
__global__ __launch_bounds__(64, 6)
void stat_denoise(const float* __restrict__ images,
                  const float* __restrict__ guidance,
                  const float* __restrict__ estimands,
                  const float* __restrict__ variance,
                  const float* __restrict__ sigma_inv,
                  const int* __restrict__ spp_ptr,
                  const half8* __restrict__ pk,
                  float* __restrict__ out)
{
    __shared__ float acc[64 * 25];            // 24 slots/thread, stride 25 (coprime w/ 32 banks)
    const int tid = threadIdx.x;
    const int tg  = tid & 7;                  // 8 t-groups of 6 centers
    const int xl  = tid >> 3;                 // 8 x-columns per block
    const int x   = (int)blockIdx.x * 8 + xl;
    const int y   = (int)blockIdx.y;
    const int t0  = tg * 6;
    float* A = acc + tid * 25;
#pragma unroll
    for (int i = 0; i < 24; ++i) A[i] = 0.0f;

    const float sppf = (float)(*spp_ptr);
    const float T2f  = 2.8070337683438042f * 2.8070337683438042f;
    const float squ  = sqrtf(2.0f * sppf);
    const float L2E  = 1.4426950408889634f;
    float sq[9];
#pragma unroll
    for (int g = 0; g < 9; ++g) sq[g] = sqrtf(sigma_inv[g] * L2E);

    const int ccol  = (y * WW + x) * TT;
    const int cbase = ccol + t0;              // t0 even -> 8B aligned, use float2 loads

    // center gate quantities (exact fp32)
    float csg[3][6], cr6[6], den_extra[6];
    float cnu2[2][6], cqe[2][6];
    {
        float ccF[6] = {};
        float r6sq[6] = {};
#pragma unroll
        for (int g = 0; g < 9; ++g) {
            F2 a0, a1, a2;
            a0.v = *(const float2*)(guidance + (size_t)g * PLANE + cbase);
            a1.v = *(const float2*)(guidance + (size_t)g * PLANE + cbase + 2);
            a2.v = *(const float2*)(guidance + (size_t)g * PLANE + cbase + 4);
#pragma unroll
            for (int r = 0; r < 6; ++r) {
                const float gv = (r < 2 ? a0.f[r] : (r < 4 ? a1.f[r - 2] : a2.f[r - 4]));
                const float s = sq[g] * gv;
                ccF[r] = fmaf(s, s, ccF[r]);
                if (g >= 3 && g < 6) csg[g - 3][r] = s;
                else                 r6sq[r] = fmaf(s, s, r6sq[r]);
            }
        }
#pragma unroll
        for (int r = 0; r < 6; ++r) cr6[r] = sqrtf(r6sq[r]);

        bool okpad[6] = {true, true, true, true, true, true};
#pragma unroll
        for (int c = 0; c < 3; ++c) {
            F2 e0, e1, e2, v0, v1, v2;
            e0.v = *(const float2*)(estimands + (size_t)c * PLANE + cbase);
            e1.v = *(const float2*)(estimands + (size_t)c * PLANE + cbase + 2);
            e2.v = *(const float2*)(estimands + (size_t)c * PLANE + cbase + 4);
            v0.v = *(const float2*)(variance  + (size_t)c * PLANE + cbase);
            v1.v = *(const float2*)(variance  + (size_t)c * PLANE + cbase + 2);
            v2.v = *(const float2*)(variance  + (size_t)c * PLANE + cbase + 4);
#pragma unroll
            for (int r = 0; r < 6; ++r) {
                const float ec = (r < 2 ? e0.f[r] : (r < 4 ? e1.f[r - 2] : e2.f[r - 4]));
                const float vc = (r < 2 ? v0.f[r] : (r < 4 ? v1.f[r - 2] : v2.f[r - 4]));
                if (c < 2) {
                    cnu2[c][r] = 2.0f * squ * ec;                       // 2*nu_c
                    cqe[c][r]  = 1.5f - fmaf(sppf * ec, ec, -T2f * vc); // 1.5 - q_c
                }
                const float dd = -2.0f - ec;                            // pad en=-2, vn=0
                okpad[r] = okpad[r] && ((dd * dd) * sppf <= T2f * vc);
            }
        }
        const int cnty = 7 - max(0, 3 - y) - max(0, y + 3 - (HH - 1));
        const int cntx = 7 - max(0, 3 - x) - max(0, x + 3 - (WW - 1));
#pragma unroll
        for (int r = 0; r < 6; ++r) {
            const int t = t0 + r;
            const int cntt = 5 - max(0, 2 - t) - max(0, t + 2 - (TT - 1));
            const float n_oob = (float)(245 - cnty * cntx * cntt);
            den_extra[r] = 1.0f + (okpad[r] ? n_oob * EXP2F(-ccF[r]) : 0.0f); // +1 = self pair
        }
    }

    // t-window bookkeeping: slot k -> t = t0 - 2 + k, k in [0,10)
    int tcl[10];
    unsigned tvm = 0;
#pragma unroll
    for (int k = 0; k < 10; ++k) {
        const int t = t0 - 2 + k;
        tcl[k] = min(max(t, 0), TT - 1);
        tvm |= ((unsigned)(t >= 0 && t < TT)) << k;
    }

    const float DC = 26.5f;   // 25 (w<2^-25 drop) + fp16 slack

    for (int dy = -3; dy <= 3; ++dy) {
        const int yy  = y + dy;
        const int ycl = min(max(yy, 0), HH - 1);
        const bool yok = (yy == ycl);
        for (int j = 0; j < 7; ++j) {
            const int xx  = x + j - 3;
            const int xcl = min(max(xx, 0), WW - 1);
            const bool cok = yok && (xx == xcl);
            const int nco = (ycl * WW + xcl) * TT;
            const half8* base = pk + nco;

            unsigned mask = 0;
#pragma unroll
            for (int k = 0; k < 10; ++k) {
                const half8 h = base[tcl[k]];
                const bool vk = cok && ((tvm >> k) & 1u);
                const float ns3 = (float)h[0];
                const float ns4 = (float)h[1];
                const float ns5 = (float)h[2];
                const float nr6 = vk ? (float)h[3] : 3.0e4f;   // poison -> dm << 0
                const float nu0 = (float)h[4];
                const float nu1 = (float)h[5];
                const float nq0 = (float)h[6];
                const float nq1 = (float)h[7];
#pragma unroll
                for (int r = 0; r < 6; ++r) {
                    const int d = k - r;
                    if (d < 0 || d > 4) continue;
                    float d0 = ns3 - csg[0][r];
                    float d1 = ns4 - csg[1][r];
                    float d2 = ns5 - csg[2][r];
                    float dist3 = d0 * d0;
                    dist3 = fmaf(d1, d1, dist3);
                    dist3 = fmaf(d2, d2, dist3);
                    const float dr = nr6 - cr6[r];
                    const float dm = DC - fmaf(dr, dr, dist3);
                    const float p0 = nu0 * cnu2[0][r];
                    const float mz0 = fmaf(0.002f, fabsf(p0), p0 + cqe[0][r]) - nq0;
                    const float p1 = nu1 * cnu2[1][r];
                    const float mz1 = fmaf(0.002f, fabsf(p1), p1 + cqe[1][r]) - nq1;
                    const float m = fminf(dm, fminf(mz0, mz1));
                    const int idx = r * 5 + d;
                    mask |= (m >= 0.0f) ? (1u << idx) : 0u;
                }
            }
            if (dy == 0 && j == 3) {      // self pairs (d==2) handled analytically
                mask &= ~0x08421084u;
            }

            while (mask) {
                const int idx = (int)__builtin_ctz(mask);
                mask &= mask - 1;
                const int r  = (idx * 13) >> 6;     // idx/5 for idx<40
                const int d  = idx - r * 5;
                const int tc = t0 + r;
                const int tn = tc + d - 2;
                // exact recompute of this pair
                float dist = 0.0f;
#pragma unroll
                for (int g = 0; g < 9; ++g) {
                    const float gn = guidance[(size_t)g * PLANE + nco + tn];
                    const float gc = guidance[(size_t)g * PLANE + ccol + tc];
                    const float df = sq[g] * (gn - gc);
                    dist = fmaf(df, df, dist);
                }
                bool pass = true;
#pragma unroll
                for (int c = 0; c < 3; ++c) {
                    const float en = estimands[(size_t)c * PLANE + nco + tn];
                    const float ec = estimands[(size_t)c * PLANE + ccol + tc];
                    const float vn = variance [(size_t)c * PLANE + nco + tn];
                    const float vc = variance [(size_t)c * PLANE + ccol + tc];
                    const float de = en - ec;
                    pass = pass && ((de * de) * sppf <= T2f * (vn + vc));
                }
                const float w = pass ? EXP2F(-dist) : 0.0f;
                float* Ar = A + r * 4;
                Ar[3] += w;
#pragma unroll
                for (int c = 0; c < 3; ++c)
                    Ar[c] = fmaf(w, images[(size_t)c * PLANE + nco + tn], Ar[c]);
            }
        }
    }

    // epilogue: out = (num + img_center) / (den + den_extra)
    F2 ia[3][3];
#pragma unroll
    for (int c = 0; c < 3; ++c) {
        ia[c][0].v = *(const float2*)(images + (size_t)c * PLANE + cbase);
        ia[c][1].v = *(const float2*)(images + (size_t)c * PLANE + cbase + 2);
        ia[c][2].v = *(const float2*)(images + (size_t)c * PLANE + cbase + 4);
    }
    float rcd[6];
#pragma unroll
    for (int r = 0; r < 6; ++r) rcd[r] = 1.0f / (A[r * 4 + 3] + den_extra[r]);
#pragma unroll
    for (int c = 0; c < 3; ++c) {
        F2 o0, o1, o2;
#pragma unroll
        for (int r = 0; r < 6; ++r) {
            const float ic = ia[c][r >> 1].f[r & 1];
            const float o  = (A[r * 4 + c] + ic) * rcd[r];
            if (r < 2)      o0.f[r]     = o;
            else if (r < 4) o1.f[r - 2] = o;
            else            o2.f[r - 4] = o;
        }
        *(float2*)(out + (size_t)c * PLANE + cbase)     = o0.v;
        *(float2*)(out + (size_t)c * PLANE + cbase + 2) = o1.v;
        *(float2*)(out + (size_t)c * PLANE + cbase + 4) = o2.v;
    }
}

extern "C" void kernel_launch(void* const* d_in, const int* in_sizes, int n_in,
                              void* d_out, int out_size, void* d_ws, size_t ws_size,
                              hipStream_t stream)
{
    (void)in_sizes; (void)n_in; (void)out_size; (void)ws_size;
    const float* images    = (const float*)d_in[0];
    const float* guidance  = (const float*)d_in[1];
    const float* estimands = (const float*)d_in[2];
    const float* variance  = (const float*)d_in[3];
    const float* sigma_inv = (const float*)d_in[4];
    const int*   spp       = (const int*)d_in[5];
    half8* pk = (half8*)d_ws;                       // PLANE * 16 B = 50.3 MB

    hipLaunchKernelGGL(prep_pack, dim3(PLANE / 1024), dim3(256), 0, stream,
                       guidance, estimands, variance, sigma_inv, spp, pk);
    hipLaunchKernelGGL(stat_denoise, dim3(WW / 8, HH), dim3(64), 0, stream,
                       images, guidance, estimands, variance, sigma_inv, spp, pk,
                       (float*)d_out);
}

// Round 3
// 1933.675 us; speedup vs baseline: 1.7583x; 1.7583x over previous
//
#include <hip/hip_runtime.h>
#include <hip/hip_fp16.h>
#include <cmath>

#define HH 256
#define WW 256
#define TT 48
#define PLANE (HH * WW * TT)

#if defined(__has_builtin)
#if __has_builtin(__builtin_amdgcn_exp2f)
#define EXP2F(x) __builtin_amdgcn_exp2f(x)
#else
#define EXP2F(x) exp2f(x)
#endif
#else
#define EXP2F(x) exp2f(x)
#endif

typedef _Float16 half8 __attribute__((ext_vector_type(8)));
union F4 { float4 v; float f[4]; };
union F2 { float2 v; float f[2]; };

// ---------------- prep: pack gate stream ----------------
// pk[pixel] = {sg3, sg4, sg5, r6, nu0, nu1, q0, q1}  (fp16, 16B)
//   sg_c = sqrt(sig_c*log2e)*g_c (c=3,4,5);  r6 = ||sg|| over channels {0,1,2,6,7,8}
//   nu_c = sqrt(2*spp)*e_c (c=0,1);          q_c = spp*e^2 - T2*v (c=0,1)
__global__ __launch_bounds__(256)
void prep_pack(const float* __restrict__ guidance,
               const float* __restrict__ estimands,
               const float* __restrict__ variance,
               const float* __restrict__ sigma_inv,
               const int* __restrict__ spp_ptr,
               half8* __restrict__ pk)
{
    const int idx = ((int)blockIdx.x * 256 + (int)threadIdx.x) * 4;
    const float sppf = (float)(*spp_ptr);
    const float T2f  = 2.8070337683438042f * 2.8070337683438042f;
    const float squ  = sqrtf(2.0f * sppf);
    const float L2E  = 1.4426950408889634f;
    float sq[9];
#pragma unroll
    for (int g = 0; g < 9; ++g) sq[g] = sqrtf(sigma_inv[g] * L2E);

    F4 gg[9];
#pragma unroll
    for (int g = 0; g < 9; ++g) gg[g].v = *(const float4*)(guidance + (size_t)g * PLANE + idx);
    F4 e0, e1, v0, v1;
    e0.v = *(const float4*)(estimands + 0 * (size_t)PLANE + idx);
    e1.v = *(const float4*)(estimands + 1 * (size_t)PLANE + idx);
    v0.v = *(const float4*)(variance  + 0 * (size_t)PLANE + idx);
    v1.v = *(const float4*)(variance  + 1 * (size_t)PLANE + idx);

#pragma unroll
    for (int s = 0; s < 4; ++s) {
        float r6sq = 0.0f;
#pragma unroll
        for (int g = 0; g < 9; ++g) {
            if (g >= 3 && g < 6) continue;
            const float t = sq[g] * gg[g].f[s];
            r6sq = fmaf(t, t, r6sq);
        }
        half8 h;
        h[0] = (_Float16)(sq[3] * gg[3].f[s]);
        h[1] = (_Float16)(sq[4] * gg[4].f[s]);
        h[2] = (_Float16)(sq[5] * gg[5].f[s]);
        h[3] = (_Float16)sqrtf(r6sq);
        h[4] = (_Float16)(squ * e0.f[s]);
        h[5] = (_Float16)(squ * e1.f[s]);
        h[6] = (_Float16)fmaf(sppf * e0.f[s], e0.f[s], -T2f * v0.f[s]);
        h[7] = (_Float16)fmaf(sppf * e1.f[s], e1.f[s], -T2f * v1.f[s]);
        pk[idx + s] = h;
    }
}

// ---------------- main ----------------
// Thread owns 1 x-column x 6 t-centers. Block: 8 x * 8 tg = 64 (1 wave), grid (W/8, H).
// No __syncthreads anywhere: LDS is pure per-thread scratch (24 slots + 1 pad).
// ROUND-3 FIX: launch_bounds (64,6)->(64,4). The 85-VGPR cap at min-waves=6 made the
// allocator spill the whole center-state array set (csg/cnu2/cqe/cr6) to scratch
// (r2: VGPR=40, FETCH +7.5GB, WRITE +1.8GB, VALUBusy 20%). Cap 128 keeps it in regs;
// VGPR ~100 -> 5 waves/SIMD (~62% occ) with zero scratch. den_extra lives in LDS
// (accumulator's initial den value), shaving 6 long-lived registers.
__global__ __launch_bounds__(64, 4)
void stat_denoise(const float* __restrict__ images,
                  const float* __restrict__ guidance,
                  const float* __restrict__ estimands,
                  const float* __restrict__ variance,
                  const float* __restrict__ sigma_inv,
                  const int* __restrict__ spp_ptr,
                  const half8* __restrict__ pk,
                  float* __restrict__ out)
{
    __shared__ float acc[64 * 25];            // 24 slots/thread, stride 25 (coprime w/ 32 banks)
    const int tid = threadIdx.x;
    const int tg  = tid & 7;                  // 8 t-groups of 6 centers
    const int xl  = tid >> 3;                 // 8 x-columns per block
    const int x   = (int)blockIdx.x * 8 + xl;
    const int y   = (int)blockIdx.y;
    const int t0  = tg * 6;
    float* A = acc + tid * 25;
#pragma unroll
    for (int i = 0; i < 24; ++i) A[i] = 0.0f;

    const float sppf = (float)(*spp_ptr);
    const float T2f  = 2.8070337683438042f * 2.8070337683438042f;
    const float squ  = sqrtf(2.0f * sppf);
    const float L2E  = 1.4426950408889634f;
    float sq[9];
#pragma unroll
    for (int g = 0; g < 9; ++g) sq[g] = sqrtf(sigma_inv[g] * L2E);

    const int ccol  = (y * WW + x) * TT;
    const int cbase = ccol + t0;              // t0 even -> 8B aligned, use float2 loads

    // center gate quantities (exact fp32); den_extra goes straight into LDS den slot
    float csg[3][6], cr6[6];
    float cnu2[2][6], cqe[2][6];
    {
        float ccF[6] = {};
        float r6sq[6] = {};
#pragma unroll
        for (int g = 0; g < 9; ++g) {
            F2 a0, a1, a2;
            a0.v = *(const float2*)(guidance + (size_t)g * PLANE + cbase);
            a1.v = *(const float2*)(guidance + (size_t)g * PLANE + cbase + 2);
            a2.v = *(const float2*)(guidance + (size_t)g * PLANE + cbase + 4);
#pragma unroll
            for (int r = 0; r < 6; ++r) {
                const float gv = (r < 2 ? a0.f[r] : (r < 4 ? a1.f[r - 2] : a2.f[r - 4]));
                const float s = sq[g] * gv;
                ccF[r] = fmaf(s, s, ccF[r]);
                if (g >= 3 && g < 6) csg[g - 3][r] = s;
                else                 r6sq[r] = fmaf(s, s, r6sq[r]);
            }
        }
#pragma unroll
        for (int r = 0; r < 6; ++r) cr6[r] = sqrtf(r6sq[r]);

        bool okpad[6] = {true, true, true, true, true, true};
#pragma unroll
        for (int c = 0; c < 3; ++c) {
            F2 e0, e1, e2, v0, v1, v2;
            e0.v = *(const float2*)(estimands + (size_t)c * PLANE + cbase);
            e1.v = *(const float2*)(estimands + (size_t)c * PLANE + cbase + 2);
            e2.v = *(const float2*)(estimands + (size_t)c * PLANE + cbase + 4);
            v0.v = *(const float2*)(variance  + (size_t)c * PLANE + cbase);
            v1.v = *(const float2*)(variance  + (size_t)c * PLANE + cbase + 2);
            v2.v = *(const float2*)(variance  + (size_t)c * PLANE + cbase + 4);
#pragma unroll
            for (int r = 0; r < 6; ++r) {
                const float ec = (r < 2 ? e0.f[r] : (r < 4 ? e1.f[r - 2] : e2.f[r - 4]));
                const float vc = (r < 2 ? v0.f[r] : (r < 4 ? v1.f[r - 2] : v2.f[r - 4]));
                if (c < 2) {
                    cnu2[c][r] = 2.0f * squ * ec;                       // 2*nu_c
                    cqe[c][r]  = 1.5f - fmaf(sppf * ec, ec, -T2f * vc); // 1.5 - q_c
                }
                const float dd = -2.0f - ec;                            // pad en=-2, vn=0
                okpad[r] = okpad[r] && ((dd * dd) * sppf <= T2f * vc);
            }
        }
        const int cnty = 7 - max(0, 3 - y) - max(0, y + 3 - (HH - 1));
        const int cntx = 7 - max(0, 3 - x) - max(0, x + 3 - (WW - 1));
#pragma unroll
        for (int r = 0; r < 6; ++r) {
            const int t = t0 + r;
            const int cntt = 5 - max(0, 2 - t) - max(0, t + 2 - (TT - 1));
            const float n_oob = (float)(245 - cnty * cntx * cntt);
            // +1 = self pair; stored as the den accumulator's initial value (LDS, per-thread)
            A[r * 4 + 3] = 1.0f + (okpad[r] ? n_oob * EXP2F(-ccF[r]) : 0.0f);
        }
    }

    // t-window bookkeeping: slot k -> t = t0 - 2 + k, k in [0,10)
    int tcl[10];
    unsigned tvm = 0;
#pragma unroll
    for (int k = 0; k < 10; ++k) {
        const int t = t0 - 2 + k;
        tcl[k] = min(max(t, 0), TT - 1);
        tvm |= ((unsigned)(t >= 0 && t < TT)) << k;
    }

    const float DC = 26.5f;   // 25 (w<2^-25 drop) + fp16 slack

    for (int dy = -3; dy <= 3; ++dy) {
        const int yy  = y + dy;
        const int ycl = min(max(yy, 0), HH - 1);
        const bool yok = (yy == ycl);
        for (int j = 0; j < 7; ++j) {
            const int xx  = x + j - 3;
            const int xcl = min(max(xx, 0), WW - 1);
            const bool cok = yok && (xx == xcl);
            const int nco = (ycl * WW + xcl) * TT;
            const half8* base = pk + nco;

            unsigned mask = 0;
#pragma unroll
            for (int k = 0; k < 10; ++k) {
                const half8 h = base[tcl[k]];
                const bool vk = cok && ((tvm >> k) & 1u);
                const float ns3 = (float)h[0];
                const float ns4 = (float)h[1];
                const float ns5 = (float)h[2];
                const float nr6 = vk ? (float)h[3] : 3.0e4f;   // poison -> dm << 0
                const float nu0 = (float)h[4];
                const float nu1 = (float)h[5];
                const float nq0 = (float)h[6];
                const float nq1 = (float)h[7];
#pragma unroll
                for (int r = 0; r < 6; ++r) {
                    const int d = k - r;
                    if (d < 0 || d > 4) continue;
                    float d0 = ns3 - csg[0][r];
                    float d1 = ns4 - csg[1][r];
                    float d2 = ns5 - csg[2][r];
                    float dist3 = d0 * d0;
                    dist3 = fmaf(d1, d1, dist3);
                    dist3 = fmaf(d2, d2, dist3);
                    const float dr = nr6 - cr6[r];
                    const float dm = DC - fmaf(dr, dr, dist3);
                    const float p0 = nu0 * cnu2[0][r];
                    const float mz0 = fmaf(0.002f, fabsf(p0), p0 + cqe[0][r]) - nq0;
                    const float p1 = nu1 * cnu2[1][r];
                    const float mz1 = fmaf(0.002f, fabsf(p1), p1 + cqe[1][r]) - nq1;
                    const float m = fminf(dm, fminf(mz0, mz1));
                    const int idx = r * 5 + d;
                    mask |= (m >= 0.0f) ? (1u << idx) : 0u;
                }
            }
            if (dy == 0 && j == 3) {      // self pairs (d==2) handled analytically
                mask &= ~0x08421084u;
            }

            while (mask) {
                const int idx = (int)__builtin_ctz(mask);
                mask &= mask - 1;
                const int r  = (idx * 13) >> 6;     // idx/5 for idx<40
                const int d  = idx - r * 5;
                const int tc = t0 + r;
                const int tn = tc + d - 2;
                // exact recompute of this pair
                float dist = 0.0f;
#pragma unroll
                for (int g = 0; g < 9; ++g) {
                    const float gn = guidance[(size_t)g * PLANE + nco + tn];
                    const float gc = guidance[(size_t)g * PLANE + ccol + tc];
                    const float df = sq[g] * (gn - gc);
                    dist = fmaf(df, df, dist);
                }
                bool pass = true;
#pragma unroll
                for (int c = 0; c < 3; ++c) {
                    const float en = estimands[(size_t)c * PLANE + nco + tn];
                    const float ec = estimands[(size_t)c * PLANE + ccol + tc];
                    const float vn = variance [(size_t)c * PLANE + nco + tn];
                    const float vc = variance [(size_t)c * PLANE + ccol + tc];
                    const float de = en - ec;
                    pass = pass && ((de * de) * sppf <= T2f * (vn + vc));
                }
                const float w = pass ? EXP2F(-dist) : 0.0f;
                float* Ar = A + r * 4;
                Ar[3] += w;
#pragma unroll
                for (int c = 0; c < 3; ++c)
                    Ar[c] = fmaf(w, images[(size_t)c * PLANE + nco + tn], Ar[c]);
            }
        }
    }

    // epilogue: out = (num + img_center) / den   (den_extra already folded into A[.+3])
    F2 ia[3][3];
#pragma unroll
    for (int c = 0; c < 3; ++c) {
        ia[c][0].v = *(const float2*)(images + (size_t)c * PLANE + cbase);
        ia[c][1].v = *(const float2*)(images + (size_t)c * PLANE + cbase + 2);
        ia[c][2].v = *(const float2*)(images + (size_t)c * PLANE + cbase + 4);
    }
    float rcd[6];
#pragma unroll
    for (int r = 0; r < 6; ++r) rcd[r] = 1.0f / A[r * 4 + 3];
#pragma unroll
    for (int c = 0; c < 3; ++c) {
        F2 o0, o1, o2;
#pragma unroll
        for (int r = 0; r < 6; ++r) {
            const float ic = ia[c][r >> 1].f[r & 1];
            const float o  = (A[r * 4 + c] + ic) * rcd[r];
            if (r < 2)      o0.f[r]     = o;
            else if (r < 4) o1.f[r - 2] = o;
            else            o2.f[r - 4] = o;
        }
        *(float2*)(out + (size_t)c * PLANE + cbase)     = o0.v;
        *(float2*)(out + (size_t)c * PLANE + cbase + 2) = o1.v;
        *(float2*)(out + (size_t)c * PLANE + cbase + 4) = o2.v;
    }
}

extern "C" void kernel_launch(void* const* d_in, const int* in_sizes, int n_in,
                              void* d_out, int out_size, void* d_ws, size_t ws_size,
                              hipStream_t stream)
{
    (void)in_sizes; (void)n_in; (void)out_size; (void)ws_size;
    const float* images    = (const float*)d_in[0];
    const float* guidance  = (const float*)d_in[1];
    const float* estimands = (const float*)d_in[2];
    const float* variance  = (const float*)d_in[3];
    const float* sigma_inv = (const float*)d_in[4];
    const int*   spp       = (const int*)d_in[5];
    half8* pk = (half8*)d_ws;                       // PLANE * 16 B = 50.3 MB

    hipLaunchKernelGGL(prep_pack, dim3(PLANE / 1024), dim3(256), 0, stream,
                       guidance, estimands, variance, sigma_inv, spp, pk);
    hipLaunchKernelGGL(stat_denoise, dim3(WW / 8, HH), dim3(64), 0, stream,
                       images, guidance, estimands, variance, sigma_inv, spp, pk,
                       (float*)d_out);
}

// Round 4
// 1930.329 us; speedup vs baseline: 1.7613x; 1.0017x over previous
//
#include <hip/hip_runtime.h>
#include <hip/hip_fp16.h>
#include <cmath>

#define HH 256
#define WW 256
#define TT 48
#define PLANE (HH * WW * TT)

#if defined(__has_builtin)
#if __has_builtin(__builtin_amdgcn_exp2f)
#define EXP2F(x) __builtin_amdgcn_exp2f(x)
#else
#define EXP2F(x) exp2f(x)
#endif
#else
#define EXP2F(x) exp2f(x)
#endif

typedef _Float16 half8 __attribute__((ext_vector_type(8)));
union F4 { float4 v; float f[4]; };
union F2 { float2 v; float f[2]; };

// ---------------- prep: pack gate stream ----------------
// pk[pixel] = {sg3, sg4, sg5, r6, nu0, nu1, q0, q1}  (fp16, 16B)
//   sg_c = sqrt(sig_c*log2e)*g_c (c=3,4,5);  r6 = ||sg|| over channels {0,1,2,6,7,8}
//   nu_c = sqrt(2*spp)*e_c (c=0,1);          q_c = spp*e^2 - T2*v (c=0,1)
__global__ __launch_bounds__(256)
void prep_pack(const float* __restrict__ guidance,
               const float* __restrict__ estimands,
               const float* __restrict__ variance,
               const float* __restrict__ sigma_inv,
               const int* __restrict__ spp_ptr,
               half8* __restrict__ pk)
{
    const int idx = ((int)blockIdx.x * 256 + (int)threadIdx.x) * 4;
    const float sppf = (float)(*spp_ptr);
    const float T2f  = 2.8070337683438042f * 2.8070337683438042f;
    const float squ  = sqrtf(2.0f * sppf);
    const float L2E  = 1.4426950408889634f;
    float sq[9];
#pragma unroll
    for (int g = 0; g < 9; ++g) sq[g] = sqrtf(sigma_inv[g] * L2E);

    F4 gg[9];
#pragma unroll
    for (int g = 0; g < 9; ++g) gg[g].v = *(const float4*)(guidance + (size_t)g * PLANE + idx);
    F4 e0, e1, v0, v1;
    e0.v = *(const float4*)(estimands + 0 * (size_t)PLANE + idx);
    e1.v = *(const float4*)(estimands + 1 * (size_t)PLANE + idx);
    v0.v = *(const float4*)(variance  + 0 * (size_t)PLANE + idx);
    v1.v = *(const float4*)(variance  + 1 * (size_t)PLANE + idx);

#pragma unroll
    for (int s = 0; s < 4; ++s) {
        float r6sq = 0.0f;
#pragma unroll
        for (int g = 0; g < 9; ++g) {
            if (g >= 3 && g < 6) continue;
            const float t = sq[g] * gg[g].f[s];
            r6sq = fmaf(t, t, r6sq);
        }
        half8 h;
        h[0] = (_Float16)(sq[3] * gg[3].f[s]);
        h[1] = (_Float16)(sq[4] * gg[4].f[s]);
        h[2] = (_Float16)(sq[5] * gg[5].f[s]);
        h[3] = (_Float16)sqrtf(r6sq);
        h[4] = (_Float16)(squ * e0.f[s]);
        h[5] = (_Float16)(squ * e1.f[s]);
        h[6] = (_Float16)fmaf(sppf * e0.f[s], e0.f[s], -T2f * v0.f[s]);
        h[7] = (_Float16)fmaf(sppf * e1.f[s], e1.f[s], -T2f * v1.f[s]);
        pk[idx + s] = h;
    }
}

// ---------------- main ----------------
// Thread owns 1 x-column x 6 t-centers. Block: 8 x * 8 tg = 64 (1 wave), grid (W/8, H).
// No __syncthreads anywhere: LDS is pure per-thread scratch (24 slots + 1 pad).
// ROUND-4 FIX: launch_bounds(64,4) only sets a MINIMUM waves/EU; the scheduler's
// occupancy heuristic still targeted 8 waves/EU (64-VGPR step) and memory-spilled
// the center state (r3: VGPR=64, WRITE 1.1GB of scratch, FETCH 5.2GB vs clean 2.3GB).
// amdgpu_waves_per_eu(4,4) PINS the target: VGPR budget 128, no incentive to shrink
// to 64. True pressure ~100 regs -> zero scratch, 4 waves/SIMD resident.
__global__ __launch_bounds__(64) __attribute__((amdgpu_waves_per_eu(4, 4)))
void stat_denoise(const float* __restrict__ images,
                  const float* __restrict__ guidance,
                  const float* __restrict__ estimands,
                  const float* __restrict__ variance,
                  const float* __restrict__ sigma_inv,
                  const int* __restrict__ spp_ptr,
                  const half8* __restrict__ pk,
                  float* __restrict__ out)
{
    __shared__ float acc[64 * 25];            // 24 slots/thread, stride 25 (coprime w/ 32 banks)
    const int tid = threadIdx.x;
    const int tg  = tid & 7;                  // 8 t-groups of 6 centers
    const int xl  = tid >> 3;                 // 8 x-columns per block
    const int x   = (int)blockIdx.x * 8 + xl;
    const int y   = (int)blockIdx.y;
    const int t0  = tg * 6;
    float* A = acc + tid * 25;
#pragma unroll
    for (int i = 0; i < 24; ++i) A[i] = 0.0f;

    const float sppf = (float)(*spp_ptr);
    const float T2f  = 2.8070337683438042f * 2.8070337683438042f;
    const float squ  = sqrtf(2.0f * sppf);
    const float L2E  = 1.4426950408889634f;
    float sq[9];
#pragma unroll
    for (int g = 0; g < 9; ++g) sq[g] = sqrtf(sigma_inv[g] * L2E);

    const int ccol  = (y * WW + x) * TT;
    const int cbase = ccol + t0;              // t0 even -> 8B aligned, use float2 loads

    // center gate quantities (exact fp32); den_extra goes straight into LDS den slot
    float csg[3][6], cr6[6];
    float cnu2[2][6], cqe[2][6];
    {
        float ccF[6] = {};
        float r6sq[6] = {};
#pragma unroll
        for (int g = 0; g < 9; ++g) {
            F2 a0, a1, a2;
            a0.v = *(const float2*)(guidance + (size_t)g * PLANE + cbase);
            a1.v = *(const float2*)(guidance + (size_t)g * PLANE + cbase + 2);
            a2.v = *(const float2*)(guidance + (size_t)g * PLANE + cbase + 4);
#pragma unroll
            for (int r = 0; r < 6; ++r) {
                const float gv = (r < 2 ? a0.f[r] : (r < 4 ? a1.f[r - 2] : a2.f[r - 4]));
                const float s = sq[g] * gv;
                ccF[r] = fmaf(s, s, ccF[r]);
                if (g >= 3 && g < 6) csg[g - 3][r] = s;
                else                 r6sq[r] = fmaf(s, s, r6sq[r]);
            }
        }
#pragma unroll
        for (int r = 0; r < 6; ++r) cr6[r] = sqrtf(r6sq[r]);

        bool okpad[6] = {true, true, true, true, true, true};
#pragma unroll
        for (int c = 0; c < 3; ++c) {
            F2 e0, e1, e2, v0, v1, v2;
            e0.v = *(const float2*)(estimands + (size_t)c * PLANE + cbase);
            e1.v = *(const float2*)(estimands + (size_t)c * PLANE + cbase + 2);
            e2.v = *(const float2*)(estimands + (size_t)c * PLANE + cbase + 4);
            v0.v = *(const float2*)(variance  + (size_t)c * PLANE + cbase);
            v1.v = *(const float2*)(variance  + (size_t)c * PLANE + cbase + 2);
            v2.v = *(const float2*)(variance  + (size_t)c * PLANE + cbase + 4);
#pragma unroll
            for (int r = 0; r < 6; ++r) {
                const float ec = (r < 2 ? e0.f[r] : (r < 4 ? e1.f[r - 2] : e2.f[r - 4]));
                const float vc = (r < 2 ? v0.f[r] : (r < 4 ? v1.f[r - 2] : v2.f[r - 4]));
                if (c < 2) {
                    cnu2[c][r] = 2.0f * squ * ec;                       // 2*nu_c
                    cqe[c][r]  = 1.5f - fmaf(sppf * ec, ec, -T2f * vc); // 1.5 - q_c
                }
                const float dd = -2.0f - ec;                            // pad en=-2, vn=0
                okpad[r] = okpad[r] && ((dd * dd) * sppf <= T2f * vc);
            }
        }
        const int cnty = 7 - max(0, 3 - y) - max(0, y + 3 - (HH - 1));
        const int cntx = 7 - max(0, 3 - x) - max(0, x + 3 - (WW - 1));
#pragma unroll
        for (int r = 0; r < 6; ++r) {
            const int t = t0 + r;
            const int cntt = 5 - max(0, 2 - t) - max(0, t + 2 - (TT - 1));
            const float n_oob = (float)(245 - cnty * cntx * cntt);
            // +1 = self pair; stored as the den accumulator's initial value (LDS, per-thread)
            A[r * 4 + 3] = 1.0f + (okpad[r] ? n_oob * EXP2F(-ccF[r]) : 0.0f);
        }
    }

    // t-window bookkeeping: slot k -> t = t0 - 2 + k, k in [0,10)
    int tcl[10];
    unsigned tvm = 0;
#pragma unroll
    for (int k = 0; k < 10; ++k) {
        const int t = t0 - 2 + k;
        tcl[k] = min(max(t, 0), TT - 1);
        tvm |= ((unsigned)(t >= 0 && t < TT)) << k;
    }

    const float DC = 26.5f;   // 25 (w<2^-25 drop) + fp16 slack

    for (int dy = -3; dy <= 3; ++dy) {
        const int yy  = y + dy;
        const int ycl = min(max(yy, 0), HH - 1);
        const bool yok = (yy == ycl);
        for (int j = 0; j < 7; ++j) {
            const int xx  = x + j - 3;
            const int xcl = min(max(xx, 0), WW - 1);
            const bool cok = yok && (xx == xcl);
            const int nco = (ycl * WW + xcl) * TT;
            const half8* base = pk + nco;

            unsigned mask = 0;
#pragma unroll
            for (int k = 0; k < 10; ++k) {
                const half8 h = base[tcl[k]];
                const bool vk = cok && ((tvm >> k) & 1u);
                const float ns3 = (float)h[0];
                const float ns4 = (float)h[1];
                const float ns5 = (float)h[2];
                const float nr6 = vk ? (float)h[3] : 3.0e4f;   // poison -> dm << 0
                const float nu0 = (float)h[4];
                const float nu1 = (float)h[5];
                const float nq0 = (float)h[6];
                const float nq1 = (float)h[7];
#pragma unroll
                for (int r = 0; r < 6; ++r) {
                    const int d = k - r;
                    if (d < 0 || d > 4) continue;
                    float d0 = ns3 - csg[0][r];
                    float d1 = ns4 - csg[1][r];
                    float d2 = ns5 - csg[2][r];
                    float dist3 = d0 * d0;
                    dist3 = fmaf(d1, d1, dist3);
                    dist3 = fmaf(d2, d2, dist3);
                    const float dr = nr6 - cr6[r];
                    const float dm = DC - fmaf(dr, dr, dist3);
                    const float p0 = nu0 * cnu2[0][r];
                    const float mz0 = fmaf(0.002f, fabsf(p0), p0 + cqe[0][r]) - nq0;
                    const float p1 = nu1 * cnu2[1][r];
                    const float mz1 = fmaf(0.002f, fabsf(p1), p1 + cqe[1][r]) - nq1;
                    const float m = fminf(dm, fminf(mz0, mz1));
                    const int idx = r * 5 + d;
                    mask |= (m >= 0.0f) ? (1u << idx) : 0u;
                }
            }
            if (dy == 0 && j == 3) {      // self pairs (d==2) handled analytically
                mask &= ~0x08421084u;
            }

            while (mask) {
                const int idx = (int)__builtin_ctz(mask);
                mask &= mask - 1;
                const int r  = (idx * 13) >> 6;     // idx/5 for idx<40
                const int d  = idx - r * 5;
                const int tc = t0 + r;
                const int tn = tc + d - 2;
                // exact recompute of this pair
                float dist = 0.0f;
#pragma unroll
                for (int g = 0; g < 9; ++g) {
                    const float gn = guidance[(size_t)g * PLANE + nco + tn];
                    const float gc = guidance[(size_t)g * PLANE + ccol + tc];
                    const float df = sq[g] * (gn - gc);
                    dist = fmaf(df, df, dist);
                }
                bool pass = true;
#pragma unroll
                for (int c = 0; c < 3; ++c) {
                    const float en = estimands[(size_t)c * PLANE + nco + tn];
                    const float ec = estimands[(size_t)c * PLANE + ccol + tc];
                    const float vn = variance [(size_t)c * PLANE + nco + tn];
                    const float vc = variance [(size_t)c * PLANE + ccol + tc];
                    const float de = en - ec;
                    pass = pass && ((de * de) * sppf <= T2f * (vn + vc));
                }
                const float w = pass ? EXP2F(-dist) : 0.0f;
                float* Ar = A + r * 4;
                Ar[3] += w;
#pragma unroll
                for (int c = 0; c < 3; ++c)
                    Ar[c] = fmaf(w, images[(size_t)c * PLANE + nco + tn], Ar[c]);
            }
        }
    }

    // epilogue: out = (num + img_center) / den   (den_extra already folded into A[.+3])
    F2 ia[3][3];
#pragma unroll
    for (int c = 0; c < 3; ++c) {
        ia[c][0].v = *(const float2*)(images + (size_t)c * PLANE + cbase);
        ia[c][1].v = *(const float2*)(images + (size_t)c * PLANE + cbase + 2);
        ia[c][2].v = *(const float2*)(images + (size_t)c * PLANE + cbase + 4);
    }
    float rcd[6];
#pragma unroll
    for (int r = 0; r < 6; ++r) rcd[r] = 1.0f / A[r * 4 + 3];
#pragma unroll
    for (int c = 0; c < 3; ++c) {
        F2 o0, o1, o2;
#pragma unroll
        for (int r = 0; r < 6; ++r) {
            const float ic = ia[c][r >> 1].f[r & 1];
            const float o  = (A[r * 4 + c] + ic) * rcd[r];
            if (r < 2)      o0.f[r]     = o;
            else if (r < 4) o1.f[r - 2] = o;
            else            o2.f[r - 4] = o;
        }
        *(float2*)(out + (size_t)c * PLANE + cbase)     = o0.v;
        *(float2*)(out + (size_t)c * PLANE + cbase + 2) = o1.v;
        *(float2*)(out + (size_t)c * PLANE + cbase + 4) = o2.v;
    }
}

extern "C" void kernel_launch(void* const* d_in, const int* in_sizes, int n_in,
                              void* d_out, int out_size, void* d_ws, size_t ws_size,
                              hipStream_t stream)
{
    (void)in_sizes; (void)n_in; (void)out_size; (void)ws_size;
    const float* images    = (const float*)d_in[0];
    const float* guidance  = (const float*)d_in[1];
    const float* estimands = (const float*)d_in[2];
    const float* variance  = (const float*)d_in[3];
    const float* sigma_inv = (const float*)d_in[4];
    const int*   spp       = (const int*)d_in[5];
    half8* pk = (half8*)d_ws;                       // PLANE * 16 B = 50.3 MB

    hipLaunchKernelGGL(prep_pack, dim3(PLANE / 1024), dim3(256), 0, stream,
                       guidance, estimands, variance, sigma_inv, spp, pk);
    hipLaunchKernelGGL(stat_denoise, dim3(WW / 8, HH), dim3(64), 0, stream,
                       images, guidance, estimands, variance, sigma_inv, spp, pk,
                       (float*)d_out);
}

// Round 5
// 1009.501 us; speedup vs baseline: 3.3679x; 1.9122x over previous
//
#include <hip/hip_runtime.h>
#include <hip/hip_fp16.h>
#include <cmath>

#define HH 256
#define WW 256
#define TT 48
#define PLANE (HH * WW * TT)

#if defined(__has_builtin)
#if __has_builtin(__builtin_amdgcn_exp2f)
#define EXP2F(x) __builtin_amdgcn_exp2f(x)
#else
#define EXP2F(x) exp2f(x)
#endif
#else
#define EXP2F(x) exp2f(x)
#endif

typedef _Float16 half8 __attribute__((ext_vector_type(8)));
union F4 { float4 v; float f[4]; };

// ---------------- prep: pack gate stream ----------------
// pk[pixel] = {sg3, sg4, sg5, r6, nu0, nu1, q0, q1}  (fp16, 16B)
//   sg_c = sqrt(sig_c*log2e)*g_c (c=3,4,5);  r6 = ||sg|| over channels {0,1,2,6,7,8}
//   nu_c = sqrt(2*spp)*e_c (c=0,1);          q_c = spp*e^2 - T2*v (c=0,1)
__global__ __launch_bounds__(256)
void prep_pack(const float* __restrict__ guidance,
               const float* __restrict__ estimands,
               const float* __restrict__ variance,
               const float* __restrict__ sigma_inv,
               const int* __restrict__ spp_ptr,
               half8* __restrict__ pk)
{
    const int idx = ((int)blockIdx.x * 256 + (int)threadIdx.x) * 4;
    const float sppf = (float)(*spp_ptr);
    const float T2f  = 2.8070337683438042f * 2.8070337683438042f;
    const float squ  = sqrtf(2.0f * sppf);
    const float L2E  = 1.4426950408889634f;
    float sq[9];
#pragma unroll
    for (int g = 0; g < 9; ++g) sq[g] = sqrtf(sigma_inv[g] * L2E);

    F4 gg[9];
#pragma unroll
    for (int g = 0; g < 9; ++g) gg[g].v = *(const float4*)(guidance + (size_t)g * PLANE + idx);
    F4 e0, e1, v0, v1;
    e0.v = *(const float4*)(estimands + 0 * (size_t)PLANE + idx);
    e1.v = *(const float4*)(estimands + 1 * (size_t)PLANE + idx);
    v0.v = *(const float4*)(variance  + 0 * (size_t)PLANE + idx);
    v1.v = *(const float4*)(variance  + 1 * (size_t)PLANE + idx);

#pragma unroll
    for (int s = 0; s < 4; ++s) {
        float r6sq = 0.0f;
#pragma unroll
        for (int g = 0; g < 9; ++g) {
            if (g >= 3 && g < 6) continue;
            const float t = sq[g] * gg[g].f[s];
            r6sq = fmaf(t, t, r6sq);
        }
        half8 h;
        h[0] = (_Float16)(sq[3] * gg[3].f[s]);
        h[1] = (_Float16)(sq[4] * gg[4].f[s]);
        h[2] = (_Float16)(sq[5] * gg[5].f[s]);
        h[3] = (_Float16)sqrtf(r6sq);
        h[4] = (_Float16)(squ * e0.f[s]);
        h[5] = (_Float16)(squ * e1.f[s]);
        h[6] = (_Float16)fmaf(sppf * e0.f[s], e0.f[s], -T2f * v0.f[s]);
        h[7] = (_Float16)fmaf(sppf * e1.f[s], e1.f[s], -T2f * v1.f[s]);
        pk[idx + s] = h;
    }
}

// ---------------- main ----------------
// ROUND-5: stop fighting the allocator, fit the budget. r2-r4 proved 64-thread
// blocks get force-squeezed to 64 VGPR (attribute hints ignored) and the 6-center
// state (~93 regs) spills ~1GB of scratch into the hot loop. r0 proved 192-thread
// blocks at (192,3) allocate honestly (84 VGPR, no spill).
// => 192 threads = 16 x-cols * 12 t-groups, 4 centers/thread:
//    center state 32 floats, sq[] -> SGPR via readfirstlane, tcl[]/tvm inlined.
//    True pressure ~65-70 -> no spill at either 64 or 72 VGPR.
//    LDS 192*17*4 = 13.0KB -> 12 blocks/CU; waves bind at ~9-10 blocks = 27-30
//    waves/CU (84-94% ceiling vs r4's 45%). Grid 4096 blocks (16/CU of work).
__global__ __launch_bounds__(192, 3)
void stat_denoise(const float* __restrict__ images,
                  const float* __restrict__ guidance,
                  const float* __restrict__ estimands,
                  const float* __restrict__ variance,
                  const float* __restrict__ sigma_inv,
                  const int* __restrict__ spp_ptr,
                  const half8* __restrict__ pk,
                  float* __restrict__ out)
{
    __shared__ float acc[192 * 17];           // 16 slots/thread + 1 pad (odd stride)
    const int tid = threadIdx.x;
    const int tg  = tid % 12;                 // 12 t-groups of 4 centers
    const int xl  = tid / 12;                 // 16 x-columns per block
    const int x   = (int)blockIdx.x * 16 + xl;
    const int y   = (int)blockIdx.y;
    const int t0  = tg * 4;
    float* A = acc + tid * 17;
#pragma unroll
    for (int i = 0; i < 16; ++i) A[i] = 0.0f;

    const float sppf = (float)(*spp_ptr);
    const float T2f  = 2.8070337683438042f * 2.8070337683438042f;
    const float squ  = sqrtf(2.0f * sppf);
    const float L2E  = 1.4426950408889634f;
    // sq[] is wave-uniform: pin to SGPRs so it costs zero VGPRs in the hot loop.
    float sq[9];
#pragma unroll
    for (int g = 0; g < 9; ++g) {
        const float s0 = sqrtf(sigma_inv[g] * L2E);
        sq[g] = __int_as_float(__builtin_amdgcn_readfirstlane(__float_as_int(s0)));
    }

    const int ccol  = (y * WW + x) * TT;
    const int cbase = ccol + t0;              // t0 % 4 == 0 -> 16B aligned, float4 loads

    // center gate quantities (exact fp32); den_extra folded into LDS den slot
    float csg[3][4], cr6[4];
    float cnu2[2][4], cqe[2][4];
    {
        float ccF[4] = {};
        float r6sq[4] = {};
#pragma unroll
        for (int g = 0; g < 9; ++g) {
            F4 a;
            a.v = *(const float4*)(guidance + (size_t)g * PLANE + cbase);
#pragma unroll
            for (int r = 0; r < 4; ++r) {
                const float s = sq[g] * a.f[r];
                ccF[r] = fmaf(s, s, ccF[r]);
                if (g >= 3 && g < 6) csg[g - 3][r] = s;
                else                 r6sq[r] = fmaf(s, s, r6sq[r]);
            }
        }
#pragma unroll
        for (int r = 0; r < 4; ++r) cr6[r] = sqrtf(r6sq[r]);

        bool okpad[4] = {true, true, true, true};
#pragma unroll
        for (int c = 0; c < 3; ++c) {
            F4 e, v;
            e.v = *(const float4*)(estimands + (size_t)c * PLANE + cbase);
            v.v = *(const float4*)(variance  + (size_t)c * PLANE + cbase);
#pragma unroll
            for (int r = 0; r < 4; ++r) {
                const float ec = e.f[r];
                const float vc = v.f[r];
                if (c < 2) {
                    cnu2[c][r] = 2.0f * squ * ec;                       // 2*nu_c
                    cqe[c][r]  = 1.5f - fmaf(sppf * ec, ec, -T2f * vc); // 1.5 - q_c
                }
                const float dd = -2.0f - ec;                            // pad en=-2, vn=0
                okpad[r] = okpad[r] && ((dd * dd) * sppf <= T2f * vc);
            }
        }
        const int cnty = 7 - max(0, 3 - y) - max(0, y + 3 - (HH - 1));
        const int cntx = 7 - max(0, 3 - x) - max(0, x + 3 - (WW - 1));
#pragma unroll
        for (int r = 0; r < 4; ++r) {
            const int t = t0 + r;
            const int cntt = 5 - max(0, 2 - t) - max(0, t + 2 - (TT - 1));
            const float n_oob = (float)(245 - cnty * cntx * cntt);
            // +1 = self pair; stored as the den accumulator's initial value (LDS, per-thread)
            A[r * 4 + 3] = 1.0f + (okpad[r] ? n_oob * EXP2F(-ccF[r]) : 0.0f);
        }
    }

    const float DC = 26.5f;   // 25 (w<2^-25 drop) + fp16 slack

    for (int dy = -3; dy <= 3; ++dy) {
        const int yy  = y + dy;
        const int ycl = min(max(yy, 0), HH - 1);
        const bool yok = (yy == ycl);
        for (int j = 0; j < 7; ++j) {
            const int xx  = x + j - 3;
            const int xcl = min(max(xx, 0), WW - 1);
            const bool cok = yok && (xx == xcl);
            const int nco = (ycl * WW + xcl) * TT;
            const half8* base = pk + nco;

            unsigned mask = 0;
#pragma unroll
            for (int k = 0; k < 8; ++k) {        // slot k -> t = t0 - 2 + k
                const int t   = t0 - 2 + k;
                const int tc2 = min(max(t, 0), TT - 1);
                const half8 h = base[tc2];
                const bool vk = cok && ((unsigned)t < (unsigned)TT);
                const float ns3 = (float)h[0];
                const float ns4 = (float)h[1];
                const float ns5 = (float)h[2];
                const float nr6 = vk ? (float)h[3] : 3.0e4f;   // poison -> dm << 0
                const float nu0 = (float)h[4];
                const float nu1 = (float)h[5];
                const float nq0 = (float)h[6];
                const float nq1 = (float)h[7];
#pragma unroll
                for (int r = 0; r < 4; ++r) {
                    const int d = k - r;
                    if (d < 0 || d > 4) continue;
                    float d0 = ns3 - csg[0][r];
                    float d1 = ns4 - csg[1][r];
                    float d2 = ns5 - csg[2][r];
                    float dist3 = d0 * d0;
                    dist3 = fmaf(d1, d1, dist3);
                    dist3 = fmaf(d2, d2, dist3);
                    const float dr = nr6 - cr6[r];
                    const float dm = DC - fmaf(dr, dr, dist3);
                    const float p0 = nu0 * cnu2[0][r];
                    const float mz0 = fmaf(0.002f, fabsf(p0), p0 + cqe[0][r]) - nq0;
                    const float p1 = nu1 * cnu2[1][r];
                    const float mz1 = fmaf(0.002f, fabsf(p1), p1 + cqe[1][r]) - nq1;
                    const float m = fminf(dm, fminf(mz0, mz1));
                    const int idx = r * 5 + d;
                    mask |= (m >= 0.0f) ? (1u << idx) : 0u;
                }
            }
            if (dy == 0 && j == 3) {      // self pairs (d==2) handled analytically
                mask &= ~0x21084u;        // bits r*5+2, r in [0,4)
            }

            while (mask) {
                const int idx = (int)__builtin_ctz(mask);
                mask &= mask - 1;
                const int r  = (idx * 13) >> 6;     // idx/5 for idx<40
                const int d  = idx - r * 5;
                const int tc = t0 + r;
                const int tn = tc + d - 2;
                // exact recompute of this pair
                float dist = 0.0f;
#pragma unroll
                for (int g = 0; g < 9; ++g) {
                    const float gn = guidance[(size_t)g * PLANE + nco + tn];
                    const float gc = guidance[(size_t)g * PLANE + ccol + tc];
                    const float df = sq[g] * (gn - gc);
                    dist = fmaf(df, df, dist);
                }
                bool pass = true;
#pragma unroll
                for (int c = 0; c < 3; ++c) {
                    const float en = estimands[(size_t)c * PLANE + nco + tn];
                    const float ec = estimands[(size_t)c * PLANE + ccol + tc];
                    const float vn = variance [(size_t)c * PLANE + nco + tn];
                    const float vc = variance [(size_t)c * PLANE + ccol + tc];
                    const float de = en - ec;
                    pass = pass && ((de * de) * sppf <= T2f * (vn + vc));
                }
                const float w = pass ? EXP2F(-dist) : 0.0f;
                float* Ar = A + r * 4;
                Ar[3] += w;
#pragma unroll
                for (int c = 0; c < 3; ++c)
                    Ar[c] = fmaf(w, images[(size_t)c * PLANE + nco + tn], Ar[c]);
            }
        }
    }

    // epilogue: out = (num + img_center) / den   (den_extra already folded into A[.+3])
    float rcd[4];
#pragma unroll
    for (int r = 0; r < 4; ++r) rcd[r] = 1.0f / A[r * 4 + 3];
#pragma unroll
    for (int c = 0; c < 3; ++c) {
        F4 ic, o;
        ic.v = *(const float4*)(images + (size_t)c * PLANE + cbase);
#pragma unroll
        for (int r = 0; r < 4; ++r)
            o.f[r] = (A[r * 4 + c] + ic.f[r]) * rcd[r];
        *(float4*)(out + (size_t)c * PLANE + cbase) = o.v;
    }
}

extern "C" void kernel_launch(void* const* d_in, const int* in_sizes, int n_in,
                              void* d_out, int out_size, void* d_ws, size_t ws_size,
                              hipStream_t stream)
{
    (void)in_sizes; (void)n_in; (void)out_size; (void)ws_size;
    const float* images    = (const float*)d_in[0];
    const float* guidance  = (const float*)d_in[1];
    const float* estimands = (const float*)d_in[2];
    const float* variance  = (const float*)d_in[3];
    const float* sigma_inv = (const float*)d_in[4];
    const int*   spp       = (const int*)d_in[5];
    half8* pk = (half8*)d_ws;                       // PLANE * 16 B = 50.3 MB

    hipLaunchKernelGGL(prep_pack, dim3(PLANE / 1024), dim3(256), 0, stream,
                       guidance, estimands, variance, sigma_inv, spp, pk);
    hipLaunchKernelGGL(stat_denoise, dim3(WW / 16, HH), dim3(192), 0, stream,
                       images, guidance, estimands, variance, sigma_inv, spp, pk,
                       (float*)d_out);
}